// Round 1
// baseline (617.461 us; speedup 1.0000x reference)
//
#include <hip/hip_runtime.h>
#include <math.h>

#define H_ 2048
#define W_ 2448
#define HW (H_*W_)          // 5013504
#define HW4 (HW/4)          // 1253376 (divisible by 256: 4896 blocks)

// f32-exact einsum coefficients (sin/cos evaluated at f32-rounded 2*pi*k/4):
//   delta_f32 = {0, 1.5707964f, 3.1415927f, 4.7123890f}
//   sin = {0, 1, -8.742278e-8, -1},  cos = {1, -4.3711388e-8, -1, +1.1924881e-8}
#define SIN2_C  (-8.7422777e-08f)   // sin(pi_f32)
#define COS1_C  (-4.3711388e-08f)   // cos(pi/2_f32)
#define COS3_C  ( 1.1924881e-08f)   // cos(3pi/2_f32)
#define TWO_PI_F   6.2831854820251465f
#define PI_HALF_F  1.5707963705062866f   // f32(pi/2)
#define PI3HALF_F  4.7123889923095703f   // f32(3*pi/2)
#define SCALE_F    2.5464790894703254f   // f32(16/(2*pi))
#define BG_THR_F   0.05f

__global__ __launch_bounds__(256)
void cg_kernel(const float* __restrict__ img, float4* __restrict__ out4) {
    int t = blockIdx.x * 256 + threadIdx.x;
    if (t >= HW4) return;
    const float4* in4 = (const float4*)img;

    // Stage all 24 plane reads (float4 each) for max memory-level parallelism.
    float4 p[8];
#pragma unroll
    for (int i = 0; i < 8; ++i) p[i] = in4[(size_t)i * HW4 + t];
    float4 g[16];
#pragma unroll
    for (int i = 0; i < 16; ++i) g[i] = in4[(size_t)(8 + i) * HW4 + t];

    float pv[8][4], gv[16][4];
#pragma unroll
    for (int i = 0; i < 8; ++i) {
        pv[i][0] = p[i].x; pv[i][1] = p[i].y; pv[i][2] = p[i].z; pv[i][3] = p[i].w;
    }
#pragma unroll
    for (int i = 0; i < 16; ++i) {
        gv[i][0] = g[i].x; gv[i][1] = g[i].y; gv[i][2] = g[i].z; gv[i][3] = g[i].w;
    }

    float col[4], row[4];
#pragma unroll
    for (int j = 0; j < 4; ++j) {
        float i0 = pv[0][j], i1 = pv[1][j], i2 = pv[2][j], i3 = pv[3][j];
        float i4 = pv[4][j], i5 = pv[5][j], i6 = pv[6][j], i7 = pv[7][j];

        // s = i1 + SIN2*i2 - i3 ; c = ((i0 + COS1*i1) - i2) + COS3*i3
        // (non-fused f32 ops: must not fma-contract, comparisons are tie-sensitive)
        float sc = __fsub_rn(__fadd_rn(i1, __fmul_rn(SIN2_C, i2)), i3);
        float cc = __fadd_rn(__fsub_rn(__fadd_rn(i0, __fmul_rn(COS1_C, i1)), i2),
                             __fmul_rn(COS3_C, i3));
        float sr = __fsub_rn(__fadd_rn(i5, __fmul_rn(SIN2_C, i6)), i7);
        float cr = __fadd_rn(__fsub_rn(__fadd_rn(i4, __fmul_rn(COS1_C, i5)), i6),
                             __fmul_rn(COS3_C, i7));

        float bgc = __fmul_rn(0.5f, __fsqrt_rn(__fadd_rn(__fmul_rn(sc, sc), __fmul_rn(cc, cc))));
        float bgr = __fmul_rn(0.5f, __fsqrt_rn(__fadd_rn(__fmul_rn(sr, sr), __fmul_rn(cr, cr))));
        float msk = (bgc > BG_THR_F || bgr > BG_THR_F) ? 1.0f : 0.0f;

        // pairwise (np-style) mean of the 8 phase-shift planes
        float thr = __fmul_rn(0.125f,
            __fadd_rn(__fadd_rn(__fadd_rn(i0, i1), __fadd_rn(i2, i3)),
                      __fadd_rn(__fadd_rn(i4, i5), __fadd_rn(i6, i7))));

        float psc = -atan2f(sc, cc);
        if (psc < 0.0f) psc = __fadd_rn(psc, TWO_PI_F);
        float psr = -atan2f(sr, cr);
        if (psr < 0.0f) psr = __fadd_rn(psr, TWO_PI_F);

        // graycode cumulative-XOR decode, ratio = {128,...,1}
        int cumc = 0, v2c = 0, k1c = 0;
        int cumr = 0, v2r = 0, k1r = 0;
#pragma unroll
        for (int i = 0; i < 8; ++i) {
            cumc ^= (gv[i][j]     > thr) ? 1 : 0;
            cumr ^= (gv[8 + i][j] > thr) ? 1 : 0;
            v2c += cumc << (7 - i);
            v2r += cumr << (7 - i);
            if (i < 7) { k1c += cumc << (6 - i); k1r += cumr << (6 - i); }
        }
        int k2c = (v2c + 1) >> 1;
        int k2r = (v2r + 1) >> 1;

        float ac;
        if (psc <= PI_HALF_F)      ac = __fmul_rn(TWO_PI_F, (float)k2c);
        else if (psc < PI3HALF_F)  ac = __fmul_rn(TWO_PI_F, (float)k1c);
        else                       ac = __fsub_rn(__fmul_rn(TWO_PI_F, (float)k2c), TWO_PI_F);
        float ar;
        if (psr <= PI_HALF_F)      ar = __fmul_rn(TWO_PI_F, (float)k2r);
        else if (psr < PI3HALF_F)  ar = __fmul_rn(TWO_PI_F, (float)k1r);
        else                       ar = __fsub_rn(__fmul_rn(TWO_PI_F, (float)k2r), TWO_PI_F);

        psc = __fadd_rn(psc, ac);
        psr = __fadd_rn(psr, ar);

        col[j] = __fmul_rn(__fmul_rn(psc, msk), SCALE_F);
        row[j] = __fmul_rn(__fmul_rn(psr, msk), SCALE_F);
    }

    // output layout (H, W, 2): pixels 4t..4t+3 -> out floats [8t .. 8t+7]
    out4[(size_t)2 * t]     = make_float4(col[0], row[0], col[1], row[1]);
    out4[(size_t)2 * t + 1] = make_float4(col[2], row[2], col[3], row[3]);
}

extern "C" void kernel_launch(void* const* d_in, const int* in_sizes, int n_in,
                              void* d_out, int out_size, void* d_ws, size_t ws_size,
                              hipStream_t stream) {
    const float* img = (const float*)d_in[0];
    float4* out = (float4*)d_out;
    dim3 grid(HW4 / 256), block(256);
    hipLaunchKernelGGL(cg_kernel, grid, block, 0, stream, img, out);
}

// Round 3
// 597.631 us; speedup vs baseline: 1.0332x; 1.0332x over previous
//
#include <hip/hip_runtime.h>
#include <math.h>

#define H_ 2048
#define W_ 2448
#define HW (H_*W_)          // 5013504
#define HW4 (HW/4)          // 1253376 = 4896 * 256 exactly

typedef float f4 __attribute__((ext_vector_type(4)));  // native vector: nontemporal-builtin OK

// f32-exact einsum coefficients (sin/cos evaluated at f32-rounded 2*pi*k/4):
//   delta_f32 = {0, 1.5707964f, 3.1415927f, 4.7123890f}
//   sin = {0, 1, -8.742278e-8, -1},  cos = {1, -4.3711388e-8, -1, +1.1924881e-8}
#define SIN2_C  (-8.7422777e-08f)   // sin(pi_f32)
#define COS1_C  (-4.3711388e-08f)   // cos(pi/2_f32)
#define COS3_C  ( 1.1924881e-08f)   // cos(3pi/2_f32)
#define TWO_PI_F   6.2831854820251465f
#define PI_HALF_F  1.5707963705062866f   // f32(pi/2)
#define PI3HALF_F  4.7123889923095703f   // f32(3*pi/2)
#define SCALE_F    2.5464790894703254f   // f32(16/(2*pi))
#define BG_THR_F   0.05f

__global__ __launch_bounds__(256)
void cg_kernel(const float* __restrict__ img, f4* __restrict__ out4) {
    const int t = blockIdx.x * 256 + threadIdx.x;   // grid covers HW4 exactly
    const f4* in4 = (const f4*)img;

    // Issue ALL loads up front (max MLP), nontemporal: every byte is touched
    // exactly once — no reason to retain in L2.
    f4 p[8];
#pragma unroll
    for (int i = 0; i < 8; ++i)
        p[i] = __builtin_nontemporal_load(&in4[(size_t)i * HW4 + t]);
    f4 g[16];
#pragma unroll
    for (int i = 0; i < 16; ++i)
        g[i] = __builtin_nontemporal_load(&in4[(size_t)(8 + i) * HW4 + t]);

    float col[4], row[4];
#pragma unroll
    for (int j = 0; j < 4; ++j) {
        const float i0 = p[0][j], i1 = p[1][j], i2 = p[2][j], i3 = p[3][j];
        const float i4 = p[4][j], i5 = p[5][j], i6 = p[6][j], i7 = p[7][j];

        // s = i1 + SIN2*i2 - i3 ; c = ((i0 + COS1*i1) - i2) + COS3*i3
        // non-fused f32 ops: comparisons downstream are tie-sensitive
        float sc = __fsub_rn(__fadd_rn(i1, __fmul_rn(SIN2_C, i2)), i3);
        float cc = __fadd_rn(__fsub_rn(__fadd_rn(i0, __fmul_rn(COS1_C, i1)), i2),
                             __fmul_rn(COS3_C, i3));
        float sr = __fsub_rn(__fadd_rn(i5, __fmul_rn(SIN2_C, i6)), i7);
        float cr = __fadd_rn(__fsub_rn(__fadd_rn(i4, __fmul_rn(COS1_C, i5)), i6),
                             __fmul_rn(COS3_C, i7));

        float bgc = __fmul_rn(0.5f, __fsqrt_rn(__fadd_rn(__fmul_rn(sc, sc), __fmul_rn(cc, cc))));
        float bgr = __fmul_rn(0.5f, __fsqrt_rn(__fadd_rn(__fmul_rn(sr, sr), __fmul_rn(cr, cr))));
        float msk = (bgc > BG_THR_F || bgr > BG_THR_F) ? 1.0f : 0.0f;

        // pairwise (np-style) mean of the 8 phase-shift planes
        float thr = __fmul_rn(0.125f,
            __fadd_rn(__fadd_rn(__fadd_rn(i0, i1), __fadd_rn(i2, i3)),
                      __fadd_rn(__fadd_rn(i4, i5), __fadd_rn(i6, i7))));

        float psc = -atan2f(sc, cc);
        if (psc < 0.0f) psc = __fadd_rn(psc, TWO_PI_F);
        float psr = -atan2f(sr, cr);
        if (psr < 0.0f) psr = __fadd_rn(psr, TWO_PI_F);

        // graycode cumulative-XOR decode, ratio = {128,...,1}
        int cumc = 0, v2c = 0, k1c = 0;
        int cumr = 0, v2r = 0, k1r = 0;
#pragma unroll
        for (int i = 0; i < 8; ++i) {
            cumc ^= (g[i][j]     > thr) ? 1 : 0;
            cumr ^= (g[8 + i][j] > thr) ? 1 : 0;
            v2c += cumc << (7 - i);
            v2r += cumr << (7 - i);
            if (i < 7) { k1c += cumc << (6 - i); k1r += cumr << (6 - i); }
        }
        int k2c = (v2c + 1) >> 1;
        int k2r = (v2r + 1) >> 1;

        float ac;
        if (psc <= PI_HALF_F)      ac = __fmul_rn(TWO_PI_F, (float)k2c);
        else if (psc < PI3HALF_F)  ac = __fmul_rn(TWO_PI_F, (float)k1c);
        else                       ac = __fsub_rn(__fmul_rn(TWO_PI_F, (float)k2c), TWO_PI_F);
        float ar;
        if (psr <= PI_HALF_F)      ar = __fmul_rn(TWO_PI_F, (float)k2r);
        else if (psr < PI3HALF_F)  ar = __fmul_rn(TWO_PI_F, (float)k1r);
        else                       ar = __fsub_rn(__fmul_rn(TWO_PI_F, (float)k2r), TWO_PI_F);

        psc = __fadd_rn(psc, ac);
        psr = __fadd_rn(psr, ar);

        col[j] = __fmul_rn(__fmul_rn(psc, msk), SCALE_F);
        row[j] = __fmul_rn(__fmul_rn(psr, msk), SCALE_F);
    }

    // output layout (H, W, 2): pixels 4t..4t+3 -> out floats [8t .. 8t+7]
    f4 o0 = {col[0], row[0], col[1], row[1]};
    f4 o1 = {col[2], row[2], col[3], row[3]};
    __builtin_nontemporal_store(o0, &out4[(size_t)2 * t]);
    __builtin_nontemporal_store(o1, &out4[(size_t)2 * t + 1]);
}

extern "C" void kernel_launch(void* const* d_in, const int* in_sizes, int n_in,
                              void* d_out, int out_size, void* d_ws, size_t ws_size,
                              hipStream_t stream) {
    const float* img = (const float*)d_in[0];
    f4* out = (f4*)d_out;
    dim3 grid(HW4 / 256), block(256);
    hipLaunchKernelGGL(cg_kernel, grid, block, 0, stream, img, out);
}